// Round 6
// baseline (1211.638 us; speedup 1.0000x reference)
//
#include <hip/hip_runtime.h>
#include <hip/hip_bf16.h>

typedef __hip_bfloat16 bf16;

#define PER_B     6291456            // 96*65536
#define EPS_F     1e-5f
#define SCALE_F   0.17677669529663687f   // 32^-0.5
#define LOGIT_MAX_F 4.605170185988092f   // log(100)

__device__ __forceinline__ float b2f(bf16 v){ return __bfloat162float(v); }
__device__ __forceinline__ bf16  f2b(float v){ return __float2bfloat16(v); }

// DT=0: buffers are bf16.  DT=1: buffers are fp32.
template<int DT> __device__ __forceinline__ float rdf(const void* p, size_t i){
  return DT ? ((const float*)p)[i] : b2f(((const bf16*)p)[i]);
}
template<int DT> __device__ __forceinline__ void wrf(void* p, size_t i, float v){
  if (DT) ((float*)p)[i] = v; else ((bf16*)p)[i] = f2b(v);
}
// paired weight load (i must be even)
template<int DT> __device__ __forceinline__ float2 rd2(const void* p, size_t i){
  if (DT) return *(const float2*)((const float*)p + i);
  unsigned u = *(const unsigned*)((const bf16*)p + i);
  return make_float2(__uint_as_float(u << 16), __uint_as_float(u & 0xffff0000u));
}

// ---------- MFMA helpers ----------
typedef __attribute__((ext_vector_type(8))) short short8v;   // 8 bf16 (4 VGPRs)
typedef __attribute__((ext_vector_type(4))) short short4v;
typedef __attribute__((ext_vector_type(4))) float f32x4;

// fp32 -> bf16 bits, round-to-nearest-even (finite inputs)
__device__ __forceinline__ short f2bs(float v){
  unsigned u = __float_as_uint(v);
  return (short)((u + 0x7fffu + ((u >> 16) & 1u)) >> 16);
}
__device__ __forceinline__ float bs2f(short s){
  return __uint_as_float(((unsigned)(unsigned short)s) << 16);
}

// load 8 contiguous weights (elements i..i+8) as bf16 bits; i % 8 == 0
template<int DT> __device__ __forceinline__ short8v ld8(const void* p, size_t i){
  short8v a;
  if (DT){
    const float* f = (const float*)p + i;
    float4 lo = *(const float4*)f;
    float4 hi = *(const float4*)(f + 4);
    a[0]=f2bs(lo.x); a[1]=f2bs(lo.y); a[2]=f2bs(lo.z); a[3]=f2bs(lo.w);
    a[4]=f2bs(hi.x); a[5]=f2bs(hi.y); a[6]=f2bs(hi.z); a[7]=f2bs(hi.w);
  } else {
    a = *(const short8v*)((const short*)p + i);
  }
  return a;
}
// load two 4-element chunks at i0 and i0+16 (elements); i0 % 4 == 0
template<int DT> __device__ __forceinline__ short8v ld4x2(const void* p, size_t i0){
  short8v a;
  if (DT){
    const float* f = (const float*)p;
    float4 lo = *(const float4*)(f + i0);
    float4 hi = *(const float4*)(f + i0 + 16);
    a[0]=f2bs(lo.x); a[1]=f2bs(lo.y); a[2]=f2bs(lo.z); a[3]=f2bs(lo.w);
    a[4]=f2bs(hi.x); a[5]=f2bs(hi.y); a[6]=f2bs(hi.z); a[7]=f2bs(hi.w);
  } else {
    const short* s = (const short*)p;
    short4v lo = *(const short4v*)(s + i0);
    short4v hi = *(const short4v*)(s + i0 + 16);
    a[0]=lo[0]; a[1]=lo[1]; a[2]=lo[2]; a[3]=lo[3];
    a[4]=hi[0]; a[5]=hi[1]; a[6]=hi[2]; a[7]=hi[3];
  }
  return a;
}

// ---------- K0: dtype detector ----------
__global__ __launch_bounds__(256) void k_detect(const void* __restrict__ x, int* __restrict__ flag){
  __shared__ int cnt;
  if (threadIdx.x == 0) cnt = 0;
  __syncthreads();
  float v = b2f(((const bf16*)x)[(size_t)threadIdx.x * 16]);
  int bad = (!(v == v)) || (fabsf(v) > 1e20f);
  if (bad) atomicAdd(&cnt, 1);
  __syncthreads();
  if (threadIdx.x == 0) *flag = (cnt >= 4) ? 1 : 0;
}

// ---------- K1: per-batch partial sums ----------
template<int DT>
__global__ __launch_bounds__(256) void k_stats_partial(const void* __restrict__ x,
    float* __restrict__ partials, const int* __restrict__ flag){
  if (*flag != DT) return;
  int blk = blockIdx.x;
  int b = blk >> 8, chunk = blk & 255;
  const int chunkN = PER_B / 256;
  size_t base = (size_t)b * PER_B + (size_t)chunk * chunkN;
  float s = 0.f, ss = 0.f;
  for (int i = threadIdx.x; i < chunkN; i += 256){
    float v = rdf<DT>(x, base + i); s += v; ss += v*v;
  }
  __shared__ float sh[512];
  sh[threadIdx.x] = s; sh[256 + threadIdx.x] = ss;
  __syncthreads();
  for (int st = 128; st > 0; st >>= 1){
    if (threadIdx.x < st){
      sh[threadIdx.x]     += sh[threadIdx.x + st];
      sh[256+threadIdx.x] += sh[256+threadIdx.x + st];
    }
    __syncthreads();
  }
  if (threadIdx.x == 0){ partials[blk*2] = sh[0]; partials[blk*2+1] = sh[256]; }
}

// ---------- K2: finalize mean/std + rescale/rebias ----------
template<int DT>
__global__ __launch_bounds__(256) void k_stats_final(const float* __restrict__ partials,
    const void* m1w, const void* m1b, const void* m2w, const void* m2b,
    float* __restrict__ stats, const int* __restrict__ flag){
  if (*flag != DT) return;
  __shared__ float sh[512];
  __shared__ float mS[4], sS[4];
  for (int b = 0; b < 4; b++){
    sh[threadIdx.x]     = partials[(b*256+threadIdx.x)*2];
    sh[256+threadIdx.x] = partials[(b*256+threadIdx.x)*2+1];
    __syncthreads();
    for (int st = 128; st > 0; st >>= 1){
      if (threadIdx.x < st){
        sh[threadIdx.x]     += sh[threadIdx.x + st];
        sh[256+threadIdx.x] += sh[256+threadIdx.x + st];
      }
      __syncthreads();
    }
    if (threadIdx.x == 0){
      float mean = sh[0] / (float)PER_B;
      float var  = sh[256] / (float)PER_B - mean*mean;
      float stdv = sqrtf(var + EPS_F);
      mS[b] = mean; sS[b] = stdv;
      stats[b] = mean; stats[4+b] = stdv;
    }
    __syncthreads();
  }
  for (int t = threadIdx.x; t < 384; t += 256){
    int b = t / 96, c = t % 96;
    stats[8+t]   = sS[b]*rdf<DT>(m1w,c) + rdf<DT>(m1b,c);
    stats[392+t] = mS[b]*rdf<DT>(m2w,c) + rdf<DT>(m2b,c);
  }
}

// ---------- K3: rel-pos bias table, transposed [h][m][n] ----------
template<int DT>
__global__ __launch_bounds__(256) void k_bias(const void* w1, const void* b1v,
    const void* w2, const void* b2v, float* __restrict__ biasT, const int* __restrict__ flag){
  if (*flag != DT) return;
  int i = blockIdx.x >> 6, j = blockIdx.x & 63;   // i = query n, j = key m
  int dy = (i>>3) - (j>>3), dx = (i&7) - (j&7);
  float fy = (float)dy, fx = (float)dx;
  float r0 = copysignf(log1pf(fabsf(fy)), fy);
  float r1 = copysignf(log1pf(fabsf(fx)), fx);
  int t = threadIdx.x;
  float hb = fmaxf(r0*rdf<DT>(w1,t*2) + r1*rdf<DT>(w1,t*2+1) + rdf<DT>(b1v,t), 0.f);
  __shared__ float sh[256];
  for (int h = 0; h < 3; h++){
    sh[t] = hb * rdf<DT>(w2, h*256+t);
    __syncthreads();
    for (int st = 128; st > 0; st >>= 1){ if (t < st) sh[t] += sh[t+st]; __syncthreads(); }
    if (t == 0) biasT[h*4096 + j*64 + i] = sh[0] + rdf<DT>(b2v, h);
    __syncthreads();
  }
}

// ---------- K4: fused AGN: x -> xn2 (bf16) ----------
template<int DT>
__global__ __launch_bounds__(256) void k_agn_fused(const void* __restrict__ x,
    const float* __restrict__ stats,
    const void* la1w, const void* la1b, const void* la2w, const void* la2b,
    const void* ta1w, const void* ta1b, const void* ta2w, const void* ta2b,
    const void* agnw, const void* agnb,
    bf16* __restrict__ xn2, const int* __restrict__ flag){
  if (*flag != DT) return;
  __shared__ float xs[400];   // 20x20 zero-padded
  __shared__ float ts[324];   // 18x18
  __shared__ float us[324];
  int idx = blockIdx.x;
  int tile = idx & 255; int bc = idx >> 8; int c = bc % 96; int b = bc / 96;
  int oy = (tile >> 4) << 4, ox = (tile & 15) << 4;
  float mean = stats[b], sd = stats[4+b];
  size_t xbase = ((size_t)bc) << 16;
  for (int it = threadIdx.x; it < 400; it += 256){
    int ly = it / 20, lx = it % 20;
    int gy = oy - 2 + ly, gx = ox - 2 + lx;
    float v = 0.f;
    if (gy >= 0 && gy < 256 && gx >= 0 && gx < 256)
      v = (rdf<DT>(x, xbase + (gy<<8) + gx) - mean) / sd;
    xs[it] = v;
  }
  float wl1[9], wt1[9], wl2[9], wt2[9];
  #pragma unroll
  for (int k = 0; k < 9; k++){
    wl1[k] = rdf<DT>(la1w, c*9+k); wt1[k] = rdf<DT>(ta1w, c*9+k);
    wl2[k] = rdf<DT>(la2w, c*9+k); wt2[k] = rdf<DT>(ta2w, c*9+k);
  }
  float bl1 = rdf<DT>(la1b, c), bt1 = rdf<DT>(ta1b, c);
  __syncthreads();
  for (int it = threadIdx.x; it < 324; it += 256){
    int ly = it / 18, lx = it % 18;
    int cy = oy - 1 + ly, cx = ox - 1 + lx;
    float a1 = 0.f, a2 = 0.f;
    if (cy >= 0 && cy < 256 && cx >= 0 && cx < 256){
      a1 = bl1; a2 = bt1;
      #pragma unroll
      for (int dy = 0; dy < 3; dy++)
        #pragma unroll
        for (int dx = 0; dx < 3; dx++){
          float v = xs[(ly+dy)*20 + lx+dx];
          a1 += v * wl1[dy*3+dx]; a2 += v * wt1[dy*3+dx];
        }
      a1 = fmaxf(a1, 0.f); a2 = fmaxf(a2, 0.f);
    }
    ts[it] = a1; us[it] = a2;
  }
  __syncthreads();
  int ty = threadIdx.x >> 4, tx0 = threadIdx.x & 15;
  float l = rdf<DT>(la2b, c), t = rdf<DT>(ta2b, c);
  #pragma unroll
  for (int dy = 0; dy < 3; dy++)
    #pragma unroll
    for (int dx = 0; dx < 3; dx++){
      l += ts[(ty+dy)*18 + tx0+dx] * wl2[dy*3+dx];
      t += us[(ty+dy)*18 + tx0+dx] * wt2[dy*3+dx];
    }
  float v = xs[(ty+2)*20 + tx0+2];
  float r = v*(rdf<DT>(agnw,c)*stats[8+bc]) + (rdf<DT>(agnb,c) + stats[392+bc]) + l + t;
  xn2[xbase + ((oy+ty)<<8) + ox + tx0] = f2b(r);
}

// ---------- K5: MFMA mega window kernel, 3 blocks/CU ----------
// LDS arena 53760 B, overlaid regions (all transitions barrier-separated):
//  CS @0      short[64][104]  = 13312  (P2-P4)  conv-q, [n][c]
//  XS @13312  short[144][104] = 29952  (P1-P2)  halo, [t][c]
//  QB @43264  short[144][8] x4 waves = 9216 (P2)  per-wave Q scratch, pos-major
//  KT @13312  short[64][104]  = 13312  (P3-P4)  K, [m][d], pre-scaled (over XS)
//  VD @26624  short[96][72]   = 13824  (P3-P4)  V, [d][m] (over XS)
//  XC @40448  short[64][104]  = 13312  (P3)     centers [n][c] (over XS/QB tail)
//  PS @40448  short[16][72] x4 waves = 9216 (P4)  per-wave P scratch (over XC)
//  OS @13312  short[64][104]  = 13312  (P5)     attn out [n][d] (over KT)
#define CS_OFF 0
#define XS_OFF 13312
#define QB_OFF 43264
#define KT_OFF 13312
#define VD_OFF 26624
#define XC_OFF 40448
#define PS_OFF 40448
#define OS_OFF 13312

template<int DT>
__global__ __launch_bounds__(256, 3) void k_attn_mega(const bf16* __restrict__ xn2,
    const void* qw, const void* qb, const void* kvw, const void* kvb,
    const void* dww, const void* dwb, const void* pw, const void* pb,
    const void* lsin, const float* __restrict__ biasT,
    const void* __restrict__ xin, const float* __restrict__ stats,
    void* __restrict__ outp, const int* __restrict__ flag){
  if (*flag != DT) return;
  __shared__ __align__(16) char smem[53760];
  int tid = threadIdx.x, wid = blockIdx.x;
  int b = wid >> 10, wy = (wid >> 5) & 31, wx = wid & 31;
  int wv = tid >> 6, ln = tid & 63;
  int r = ln & 15, q = ln >> 4;

  // ---- P1: stage reflected 12x12 halo, pixel-major xs[t][c].
  // Lane->channel assignment XORed by (t>>3)&7: spreads the 52-dword-stride
  // column writes from 8-way to ~2-way bank conflict; layout stays standard.
  {
    short* xs = (short*)(smem + XS_OFF);
    for (int it = tid; it < 13824; it += 256){
      int t = it % 144, craw = it / 144;
      int c = craw ^ ((t >> 3) & 7);
      int ty = (wy<<3) - 2 + t/12, tx = (wx<<3) - 2 + t%12;
      ty = ty < 0 ? -ty : (ty > 255 ? 510 - ty : ty);
      tx = tx < 0 ? -tx : (tx > 255 ? 510 - tx : tx);
      xs[t*104 + c] = ((const short*)xn2)[(((size_t)(b*96 + c))<<16) + (ty<<8) + tx];
    }
  }
  __syncthreads();

  // ---- P2: Q GEMM (M=96,N=144,K=96) + 5x5 dwconv via pos-major scratch.
  // Per-wave scratch Qb[pos][8ch] (16B rows): each conv tap is ONE
  // ds_read_b128 delivering 8 channels (25 reads/half vs 200 scalar).
  {
    const short* xs = (const short*)(smem + XS_OFF);
    short* Qb = (short*)(smem + QB_OFF) + wv*1152;   // [144][8] shorts
    short* cs = (short*)(smem + CS_OFF);
    int ty0 = (ln>>3)+2, tx0 = (ln&7)+2;
    for (int mt = wv; mt < 6; mt += 4){
      short8v aw[3];
      #pragma unroll
      for (int kt = 0; kt < 3; kt++)
        aw[kt] = ld8<DT>(qw, (size_t)(16*mt + r)*96 + 32*kt + 8*q);
      float qb4[4];
      #pragma unroll
      for (int j = 0; j < 4; j++) qb4[j] = rdf<DT>(qb, 16*mt + 4*q + j);
      float accs[9][4];
      #pragma unroll
      for (int nt = 0; nt < 9; nt++){
        f32x4 acc = {0.f,0.f,0.f,0.f};
        #pragma unroll
        for (int kt = 0; kt < 3; kt++){
          short8v bx = *(const short8v*)(xs + (16*nt + r)*104 + 32*kt + 8*q);
          acc = __builtin_amdgcn_mfma_f32_16x16x32_bf16(aw[kt], bx, acc, 0, 0, 0);
        }
        #pragma unroll
        for (int j = 0; j < 4; j++) accs[nt][j] = acc[j] + qb4[j];
      }
      #pragma unroll
      for (int hf = 0; hf < 2; hf++){
        // write half hf: channel rows 8hf..8hf+7 (lanes q>>1 == hf)
        if ((q >> 1) == hf){
          int cl = 4*(q & 1);
          #pragma unroll
          for (int nt = 0; nt < 9; nt++)
            #pragma unroll
            for (int j = 0; j < 4; j++)
              Qb[(16*nt + r)*8 + cl + j] = f2bs(accs[nt][j]);
        }
        asm volatile("s_waitcnt lgkmcnt(0)" ::: "memory");
        // dwconv: 25 taps x ds_read_b128 (8 channels at once)
        float acc8[8];
        #pragma unroll
        for (int k = 0; k < 8; k++) acc8[k] = rdf<DT>(dwb, 16*mt + 8*hf + k);
        #pragma unroll
        for (int dy = -2; dy <= 2; dy++)
          #pragma unroll
          for (int dx = -2; dx <= 2; dx++){
            int pos = (ty0+dy)*12 + tx0+dx;
            short8v v = *(const short8v*)(Qb + pos*8);
            #pragma unroll
            for (int k = 0; k < 8; k++)
              acc8[k] += bs2f(v[k]) * rdf<DT>(dww, (16*mt + 8*hf + k)*25 + (dy+2)*5 + dx+2);
          }
        short8v outv;
        #pragma unroll
        for (int k = 0; k < 8; k++) outv[k] = f2bs(acc8[k]);
        *(short8v*)(cs + ln*104 + 16*mt + 8*hf) = outv;
        asm volatile("s_waitcnt lgkmcnt(0)" ::: "memory");
      }
    }
  }
  __syncthreads();

  // ---- P3: re-stage centers xc[n][c] (px^row write order: 16-way -> 2-way),
  //          then KV GEMM (M=192,N=64,K=96)
  {
    short* xc = (short*)(smem + XC_OFF);
    for (int it = tid; it < 768; it += 256){
      int c = it >> 3, row = it & 7;
      const short* src = (const short*)xn2 + (((size_t)(b*96 + c))<<16)
                         + (((wy<<3)+row)<<8) + (wx<<3);
      short8v v = *(const short8v*)src;
      #pragma unroll
      for (int k = 0; k < 8; k++){
        int pe = k ^ row;
        xc[(row*8+pe)*104 + c] = v[pe];
      }
    }
  }
  __syncthreads();
  {
    const short* xc = (const short*)(smem + XC_OFF);
    short* Kt = (short*)(smem + KT_OFF);
    short* Vd = (short*)(smem + VD_OFF);
    for (int mtk = wv; mtk < 12; mtk += 4){
      short8v aw[3];
      #pragma unroll
      for (int kt = 0; kt < 3; kt++)
        aw[kt] = ld8<DT>(kvw, (size_t)(16*mtk + r)*96 + 32*kt + 8*q);
      float bb[4];
      #pragma unroll
      for (int j = 0; j < 4; j++) bb[j] = rdf<DT>(kvb, 16*mtk + 4*q + j);
      for (int nt = 0; nt < 4; nt++){
        f32x4 acc = {0.f,0.f,0.f,0.f};
        #pragma unroll
        for (int kt = 0; kt < 3; kt++){
          short8v bx = *(const short8v*)(xc + (16*nt + r)*104 + 32*kt + 8*q);
          acc = __builtin_amdgcn_mfma_f32_16x16x32_bf16(aw[kt], bx, acc, 0, 0, 0);
        }
        if (mtk < 6){
          short4v kv;
          #pragma unroll
          for (int j = 0; j < 4; j++) kv[j] = f2bs((acc[j] + bb[j]) * SCALE_F);
          *(short4v*)(Kt + (16*nt + r)*104 + 16*mtk + 4*q) = kv;
        } else {
          #pragma unroll
          for (int j = 0; j < 4; j++)
            Vd[(16*(mtk-6) + 4*q + j)*72 + 16*nt + r] = f2bs(acc[j] + bb[j]);
        }
      }
    }
  }
  __syncthreads();

  // ---- P4: attention. Wave wv owns n-tile nt=wv for all 3 heads.
  float o_save[24];
  {
    const short* cs = (const short*)(smem + CS_OFF);
    const short* Kt = (const short*)(smem + KT_OFF);
    const short* Vd = (const short*)(smem + VD_OFF);
    short* Psw = (short*)(smem + PS_OFF) + wv*1152;   // [16][72]
    float lsv = __expf(fminf(rdf<DT>(lsin, 0), LOGIT_MAX_F));
    #pragma unroll
    for (int h = 0; h < 3; h++){
      short8v qa = *(const short8v*)(cs + (16*wv + r)*104 + 32*h + 8*q);
      f32x4 s[4];
      #pragma unroll
      for (int mt = 0; mt < 4; mt++){
        short8v kb = *(const short8v*)(Kt + (16*mt + r)*104 + 32*h + 8*q);
        f32x4 z = {0.f,0.f,0.f,0.f};
        s[mt] = __builtin_amdgcn_mfma_f32_16x16x32_bf16(qa, kb, z, 0, 0, 0);
      }
      float l[4][4];
      #pragma unroll
      for (int mt = 0; mt < 4; mt++){
        float4 bv = *(const float4*)(biasT + h*4096 + (16*mt + r)*64 + 16*wv + 4*q);
        l[mt][0] = s[mt][0]*lsv + bv.x;
        l[mt][1] = s[mt][1]*lsv + bv.y;
        l[mt][2] = s[mt][2]*lsv + bv.z;
        l[mt][3] = s[mt][3]*lsv + bv.w;
      }
      float mx[4], sm[4];
      #pragma unroll
      for (int j = 0; j < 4; j++){
        float m0 = fmaxf(fmaxf(l[0][j], l[1][j]), fmaxf(l[2][j], l[3][j]));
        m0 = fmaxf(m0, __shfl_xor(m0, 1));
        m0 = fmaxf(m0, __shfl_xor(m0, 2));
        m0 = fmaxf(m0, __shfl_xor(m0, 4));
        m0 = fmaxf(m0, __shfl_xor(m0, 8));
        mx[j] = m0; sm[j] = 0.f;
      }
      #pragma unroll
      for (int mt = 0; mt < 4; mt++)
        #pragma unroll
        for (int j = 0; j < 4; j++){
          float p = __expf(l[mt][j] - mx[j]);
          sm[j] += p;
          Psw[(4*q+j)*72 + 16*mt + r] = f2bs(p);
        }
      #pragma unroll
      for (int j = 0; j < 4; j++){
        sm[j] += __shfl_xor(sm[j], 1);
        sm[j] += __shfl_xor(sm[j], 2);
        sm[j] += __shfl_xor(sm[j], 4);
        sm[j] += __shfl_xor(sm[j], 8);
      }
      float inv[4];
      #pragma unroll
      for (int j = 0; j < 4; j++) inv[j] = 1.f / sm[j];
      asm volatile("s_waitcnt lgkmcnt(0)" ::: "memory");
      short8v pa0 = *(const short8v*)(Psw + r*72 + 8*q);
      short8v pa1 = *(const short8v*)(Psw + r*72 + 32 + 8*q);
      #pragma unroll
      for (int dt = 0; dt < 2; dt++){
        f32x4 o = {0.f,0.f,0.f,0.f};
        short8v vb0 = *(const short8v*)(Vd + (32*h + 16*dt + r)*72 + 8*q);
        short8v vb1 = *(const short8v*)(Vd + (32*h + 16*dt + r)*72 + 32 + 8*q);
        o = __builtin_amdgcn_mfma_f32_16x16x32_bf16(pa0, vb0, o, 0, 0, 0);
        o = __builtin_amdgcn_mfma_f32_16x16x32_bf16(pa1, vb1, o, 0, 0, 0);
        #pragma unroll
        for (int j = 0; j < 4; j++) o_save[h*8 + dt*4 + j] = o[j] * inv[j];
      }
      asm volatile("s_waitcnt lgkmcnt(0)" ::: "memory");
    }
  }
  __syncthreads();

  // ---- write osT[n][d] over KT region
  {
    short* os = (short*)(smem + OS_OFF);
    #pragma unroll
    for (int h = 0; h < 3; h++)
      #pragma unroll
      for (int dt = 0; dt < 2; dt++)
        #pragma unroll
        for (int j = 0; j < 4; j++)
          os[(16*wv + 4*q + j)*104 + 32*h + 16*dt + r] = f2bs(o_save[h*8 + dt*4 + j]);
  }
  __syncthreads();

  // ---- P5: proj GEMM (M=96,N=64,K=96) + residual epilogue
  {
    const short* os = (const short*)(smem + OS_OFF);
    short8v ob[3];
    #pragma unroll
    for (int kt = 0; kt < 3; kt++)
      ob[kt] = *(const short8v*)(os + (16*wv + r)*104 + 32*kt + 8*q);
    for (int mt = 0; mt < 6; mt++){
      f32x4 acc = {0.f,0.f,0.f,0.f};
      #pragma unroll
      for (int kt = 0; kt < 3; kt++){
        short8v aw = ld8<DT>(pw, (size_t)(16*mt + r)*96 + 32*kt + 8*q);
        acc = __builtin_amdgcn_mfma_f32_16x16x32_bf16(aw, ob[kt], acc, 0, 0, 0);
      }
      #pragma unroll
      for (int j = 0; j < 4; j++){
        int oc = 16*mt + 4*q + j;
        int n  = 16*wv + r;
        int gy = (wy<<3) + (n>>3), gx = (wx<<3) + (n&7);
        size_t gi = (((size_t)(b*96 + oc))<<16) + (gy<<8) + gx;
        float a = acc[j] + rdf<DT>(pb, oc);
        float x1 = rdf<DT>(xin, gi) + a*stats[8 + b*96 + oc] + stats[392 + b*96 + oc];
        wrf<DT>(outp, gi, x1);
      }
    }
  }
}

// ---------- K6: MFMA MLP v2, N-blocked ----------
template<int DT>
__global__ __launch_bounds__(256) void k_mlp_mfma(void* __restrict__ io,
    const void* w1, const void* b1, const void* w2, const void* b2v,
    const int* __restrict__ flag){
  if (*flag != DT) return;
  __shared__ __align__(16) short x1s[256*104];   // [pixel][channel], 53248 B
  int blk = blockIdx.x; int b = blk >> 8; int pix0 = (blk & 255) << 8;
  int tid = threadIdx.x;

  for (int c = 0; c < 96; c++){
    size_t gi = (((size_t)(b*96 + c))<<16) + pix0 + tid;
    short v = DT ? f2bs(((const float*)io)[gi]) : ((const short*)io)[gi];
    x1s[tid*104 + c] = v;
  }
  __syncthreads();

  int wv = tid >> 6, l = tid & 63;
  int r = l & 15, q = l >> 4;
  int pbase = wv << 6;

  f32x4 acc2[6][4];
  #pragma unroll
  for (int mt = 0; mt < 6; mt++)
    #pragma unroll
    for (int nt = 0; nt < 4; nt++)
      acc2[mt][nt] = (f32x4){0.f,0.f,0.f,0.f};

  #pragma unroll 2
  for (int t = 0; t < 12; t++){
    short8v aA[3], aB[3];
    #pragma unroll
    for (int kt = 0; kt < 3; kt++){
      aA[kt] = ld8<DT>(w1, (size_t)(32*t + r)*96      + 32*kt + 8*q);
      aB[kt] = ld8<DT>(w1, (size_t)(32*t + 16 + r)*96 + 32*kt + 8*q);
    }
    float bA[4], bB[4];
    #pragma unroll
    for (int j = 0; j < 4; j++){
      bA[j] = rdf<DT>(b1, 32*t + 4*q + j);
      bB[j] = rdf<DT>(b1, 32*t + 16 + 4*q + j);
    }
    f32x4 a1A[4], a1B[4];
    #pragma unroll
    for (int nt = 0; nt < 4; nt++){
      a1A[nt] = (f32x4){0.f,0.f,0.f,0.f};
      a1B[nt] = (f32x4){0.f,0.f,0.f,0.f};
    }
    #pragma unroll
    for (int kt = 0; kt < 3; kt++){
      #pragma unroll
      for (int nt = 0; nt < 4; nt++){
        short8v bx = *(const short8v*)&x1s[(pbase + 16*nt + r)*104 + 32*kt + 8*q];
        a1A[nt] = __builtin_amdgcn_mfma_f32_16x16x32_bf16(aA[kt], bx, a1A[nt], 0, 0, 0);
        a1B[nt] = __builtin_amdgcn_mfma_f32_16x16x32_bf16(aB[kt], bx, a1B[nt], 0, 0, 0);
      }
    }
    short8v B2[4];
    #pragma unroll
    for (int nt = 0; nt < 4; nt++){
      short8v h;
      #pragma unroll
      for (int j = 0; j < 4; j++){
        h[j]   = f2bs(fmaxf(a1A[nt][j] + bA[j], 0.f));
        h[4+j] = f2bs(fmaxf(a1B[nt][j] + bB[j], 0.f));
      }
      B2[nt] = h;
    }
    #pragma unroll
    for (int mt = 0; mt < 6; mt++){
      short8v wA = ld4x2<DT>(w2, (size_t)(16*mt + r)*384 + 32*t + 4*q);
      #pragma unroll
      for (int nt = 0; nt < 4; nt++)
        acc2[mt][nt] = __builtin_amdgcn_mfma_f32_16x16x32_bf16(wA, B2[nt], acc2[mt][nt], 0, 0, 0);
    }
  }

  #pragma unroll
  for (int mt = 0; mt < 6; mt++)
    #pragma unroll
    for (int nt = 0; nt < 4; nt++)
      #pragma unroll
      for (int j = 0; j < 4; j++){
        int oc = 16*mt + 4*q + j;
        int pl = pbase + 16*nt + r;
        size_t gi = (((size_t)(b*96 + oc))<<16) + pix0 + pl;
        float v = acc2[mt][nt][j] + rdf<DT>(b2v, oc);
        if (DT){
          ((float*)io)[gi] = ((const float*)io)[gi] + v;
        } else {
          ((bf16*)io)[gi] = f2b(bs2f(x1s[pl*104 + oc]) + v);
        }
      }
}

extern "C" void kernel_launch(void* const* d_in, const int* in_sizes, int n_in,
                              void* d_out, int out_size, void* d_ws, size_t ws_size,
                              hipStream_t stream) {
  const void* x      = d_in[0];
  const void* agnw   = d_in[1];
  const void* agnb   = d_in[2];
  const void* meta1w = d_in[3];
  const void* meta1b = d_in[4];
  const void* meta2w = d_in[5];
  const void* meta2b = d_in[6];
  const void* la1w   = d_in[7];
  const void* la1b   = d_in[8];
  const void* la2w   = d_in[9];
  const void* la2b   = d_in[10];
  const void* ta1w   = d_in[11];
  const void* ta1b   = d_in[12];
  const void* ta2w   = d_in[13];
  const void* ta2b   = d_in[14];
  const void* qw     = d_in[15];
  const void* qb     = d_in[16];
  const void* kvw    = d_in[17];
  const void* kvb    = d_in[18];
  const void* dww    = d_in[19];
  const void* dwb    = d_in[20];
  const void* pw     = d_in[21];
  const void* pb     = d_in[22];
  const void* lsin   = d_in[23];
  const void* rpw1   = d_in[24];
  const void* rpb1   = d_in[25];
  const void* rpw2   = d_in[26];
  const void* rpb2   = d_in[27];
  const void* m1w    = d_in[28];
  const void* m1b    = d_in[29];
  const void* m2w    = d_in[30];
  const void* m2b    = d_in[31];

  // ws: flag @0 | partials @256 | stats @8448 | biasT @12288 | xn2 @65536 (48MB)
  char* ws = (char*)d_ws;
  int*   flag     = (int*)ws;
  float* partials = (float*)(ws + 256);
  float* stats    = (float*)(ws + 8448);
  float* biasT    = (float*)(ws + 12288);
  bf16*  xn2      = (bf16*)(ws + 65536);

  k_detect<<<1, 256, 0, stream>>>(x, flag);

  // bf16 variant
  k_stats_partial<0><<<1024, 256, 0, stream>>>(x, partials, flag);
  k_stats_final<0>  <<<1,    256, 0, stream>>>(partials, meta1w, meta1b, meta2w, meta2b, stats, flag);
  k_bias<0>         <<<4096, 256, 0, stream>>>(rpw1, rpb1, rpw2, rpb2, biasT, flag);
  k_agn_fused<0>    <<<98304,256, 0, stream>>>(x, stats, la1w, la1b, la2w, la2b,
                                               ta1w, ta1b, ta2w, ta2b, agnw, agnb, xn2, flag);
  k_attn_mega<0>    <<<4096, 256, 0, stream>>>(xn2, qw, qb, kvw, kvb, dww, dwb, pw, pb,
                                               lsin, biasT, x, stats, d_out, flag);
  k_mlp_mfma<0>     <<<1024, 256, 0, stream>>>(d_out, m1w, m1b, m2w, m2b, flag);

  // fp32 variant
  k_stats_partial<1><<<1024, 256, 0, stream>>>(x, partials, flag);
  k_stats_final<1>  <<<1,    256, 0, stream>>>(partials, meta1w, meta1b, meta2w, meta2b, stats, flag);
  k_bias<1>         <<<4096, 256, 0, stream>>>(rpw1, rpb1, rpw2, rpb2, biasT, flag);
  k_agn_fused<1>    <<<98304,256, 0, stream>>>(x, stats, la1w, la1b, la2w, la2b,
                                               ta1w, ta1b, ta2w, ta2b, agnw, agnb, xn2, flag);
  k_attn_mega<1>    <<<4096, 256, 0, stream>>>(xn2, qw, qb, kvw, kvb, dww, dwb, pw, pb,
                                               lsin, biasT, x, stats, d_out, flag);
  k_mlp_mfma<1>     <<<1024, 256, 0, stream>>>(d_out, m1w, m1b, m2w, m2b, flag);
}

// Round 7
// 1007.180 us; speedup vs baseline: 1.2030x; 1.2030x over previous
//
#include <hip/hip_runtime.h>
#include <hip/hip_bf16.h>

typedef __hip_bfloat16 bf16;

#define PER_B     6291456            // 96*65536
#define EPS_F     1e-5f
#define SCALE_F   0.17677669529663687f   // 32^-0.5
#define LOGIT_MAX_F 4.605170185988092f   // log(100)

__device__ __forceinline__ float b2f(bf16 v){ return __bfloat162float(v); }
__device__ __forceinline__ bf16  f2b(float v){ return __float2bfloat16(v); }

// DT=0: buffers are bf16.  DT=1: buffers are fp32.
template<int DT> __device__ __forceinline__ float rdf(const void* p, size_t i){
  return DT ? ((const float*)p)[i] : b2f(((const bf16*)p)[i]);
}
template<int DT> __device__ __forceinline__ void wrf(void* p, size_t i, float v){
  if (DT) ((float*)p)[i] = v; else ((bf16*)p)[i] = f2b(v);
}
// paired weight load (i must be even)
template<int DT> __device__ __forceinline__ float2 rd2(const void* p, size_t i){
  if (DT) return *(const float2*)((const float*)p + i);
  unsigned u = *(const unsigned*)((const bf16*)p + i);
  return make_float2(__uint_as_float(u << 16), __uint_as_float(u & 0xffff0000u));
}

// ---------- MFMA helpers ----------
typedef __attribute__((ext_vector_type(8))) short short8v;   // 8 bf16 (4 VGPRs)
typedef __attribute__((ext_vector_type(4))) short short4v;
typedef __attribute__((ext_vector_type(4))) float f32x4;

// fp32 -> bf16 bits, round-to-nearest-even (finite inputs)
__device__ __forceinline__ short f2bs(float v){
  unsigned u = __float_as_uint(v);
  return (short)((u + 0x7fffu + ((u >> 16) & 1u)) >> 16);
}
__device__ __forceinline__ float bs2f(short s){
  return __uint_as_float(((unsigned)(unsigned short)s) << 16);
}

// load 8 contiguous weights (elements i..i+8) as bf16 bits; i % 8 == 0
template<int DT> __device__ __forceinline__ short8v ld8(const void* p, size_t i){
  short8v a;
  if (DT){
    const float* f = (const float*)p + i;
    float4 lo = *(const float4*)f;
    float4 hi = *(const float4*)(f + 4);
    a[0]=f2bs(lo.x); a[1]=f2bs(lo.y); a[2]=f2bs(lo.z); a[3]=f2bs(lo.w);
    a[4]=f2bs(hi.x); a[5]=f2bs(hi.y); a[6]=f2bs(hi.z); a[7]=f2bs(hi.w);
  } else {
    a = *(const short8v*)((const short*)p + i);
  }
  return a;
}
// load two 4-element chunks at i0 and i0+16 (elements); i0 % 4 == 0
template<int DT> __device__ __forceinline__ short8v ld4x2(const void* p, size_t i0){
  short8v a;
  if (DT){
    const float* f = (const float*)p;
    float4 lo = *(const float4*)(f + i0);
    float4 hi = *(const float4*)(f + i0 + 16);
    a[0]=f2bs(lo.x); a[1]=f2bs(lo.y); a[2]=f2bs(lo.z); a[3]=f2bs(lo.w);
    a[4]=f2bs(hi.x); a[5]=f2bs(hi.y); a[6]=f2bs(hi.z); a[7]=f2bs(hi.w);
  } else {
    const short* s = (const short*)p;
    short4v lo = *(const short4v*)(s + i0);
    short4v hi = *(const short4v*)(s + i0 + 16);
    a[0]=lo[0]; a[1]=lo[1]; a[2]=lo[2]; a[3]=lo[3];
    a[4]=hi[0]; a[5]=hi[1]; a[6]=hi[2]; a[7]=hi[3];
  }
  return a;
}

// ---------- K0: dtype detector ----------
__global__ __launch_bounds__(256) void k_detect(const void* __restrict__ x, int* __restrict__ flag){
  __shared__ int cnt;
  if (threadIdx.x == 0) cnt = 0;
  __syncthreads();
  float v = b2f(((const bf16*)x)[(size_t)threadIdx.x * 16]);
  int bad = (!(v == v)) || (fabsf(v) > 1e20f);
  if (bad) atomicAdd(&cnt, 1);
  __syncthreads();
  if (threadIdx.x == 0) *flag = (cnt >= 4) ? 1 : 0;
}

// ---------- K1: per-batch partial sums (vectorized loads) ----------
template<int DT>
__global__ __launch_bounds__(256) void k_stats_partial(const void* __restrict__ x,
    float* __restrict__ partials, const int* __restrict__ flag){
  if (*flag != DT) return;
  int blk = blockIdx.x;
  int b = blk >> 8, chunk = blk & 255;
  const int chunkN = PER_B / 256;
  size_t base = (size_t)b * PER_B + (size_t)chunk * chunkN;
  float s = 0.f, ss = 0.f;
  if (DT){
    const float4* p4 = (const float4*)((const float*)x + base);
    for (int i = threadIdx.x; i < chunkN/4; i += 256){
      float4 v = p4[i];
      s  += v.x + v.y + v.z + v.w;
      ss += v.x*v.x + v.y*v.y + v.z*v.z + v.w*v.w;
    }
  } else {
    const short8v* p8 = (const short8v*)((const short*)x + base);
    for (int i = threadIdx.x; i < chunkN/8; i += 256){
      short8v v = p8[i];
      #pragma unroll
      for (int k = 0; k < 8; k++){
        float f = bs2f(v[k]); s += f; ss += f*f;
      }
    }
  }
  __shared__ float sh[512];
  sh[threadIdx.x] = s; sh[256 + threadIdx.x] = ss;
  __syncthreads();
  for (int st = 128; st > 0; st >>= 1){
    if (threadIdx.x < st){
      sh[threadIdx.x]     += sh[threadIdx.x + st];
      sh[256+threadIdx.x] += sh[256+threadIdx.x + st];
    }
    __syncthreads();
  }
  if (threadIdx.x == 0){ partials[blk*2] = sh[0]; partials[blk*2+1] = sh[256]; }
}

// ---------- K2: finalize mean/std + rescale/rebias ----------
template<int DT>
__global__ __launch_bounds__(256) void k_stats_final(const float* __restrict__ partials,
    const void* m1w, const void* m1b, const void* m2w, const void* m2b,
    float* __restrict__ stats, const int* __restrict__ flag){
  if (*flag != DT) return;
  __shared__ float sh[512];
  __shared__ float mS[4], sS[4];
  for (int b = 0; b < 4; b++){
    sh[threadIdx.x]     = partials[(b*256+threadIdx.x)*2];
    sh[256+threadIdx.x] = partials[(b*256+threadIdx.x)*2+1];
    __syncthreads();
    for (int st = 128; st > 0; st >>= 1){
      if (threadIdx.x < st){
        sh[threadIdx.x]     += sh[threadIdx.x + st];
        sh[256+threadIdx.x] += sh[256+threadIdx.x + st];
      }
      __syncthreads();
    }
    if (threadIdx.x == 0){
      float mean = sh[0] / (float)PER_B;
      float var  = sh[256] / (float)PER_B - mean*mean;
      float stdv = sqrtf(var + EPS_F);
      mS[b] = mean; sS[b] = stdv;
      stats[b] = mean; stats[4+b] = stdv;
    }
    __syncthreads();
  }
  for (int t = threadIdx.x; t < 384; t += 256){
    int b = t / 96, c = t % 96;
    stats[8+t]   = sS[b]*rdf<DT>(m1w,c) + rdf<DT>(m1b,c);
    stats[392+t] = mS[b]*rdf<DT>(m2w,c) + rdf<DT>(m2b,c);
  }
}

// ---------- K3: rel-pos bias table, transposed [h][m][n] ----------
template<int DT>
__global__ __launch_bounds__(256) void k_bias(const void* w1, const void* b1v,
    const void* w2, const void* b2v, float* __restrict__ biasT, const int* __restrict__ flag){
  if (*flag != DT) return;
  int i = blockIdx.x >> 6, j = blockIdx.x & 63;   // i = query n, j = key m
  int dy = (i>>3) - (j>>3), dx = (i&7) - (j&7);
  float fy = (float)dy, fx = (float)dx;
  float r0 = copysignf(log1pf(fabsf(fy)), fy);
  float r1 = copysignf(log1pf(fabsf(fx)), fx);
  int t = threadIdx.x;
  float hb = fmaxf(r0*rdf<DT>(w1,t*2) + r1*rdf<DT>(w1,t*2+1) + rdf<DT>(b1v,t), 0.f);
  __shared__ float sh[256];
  for (int h = 0; h < 3; h++){
    sh[t] = hb * rdf<DT>(w2, h*256+t);
    __syncthreads();
    for (int st = 128; st > 0; st >>= 1){ if (t < st) sh[t] += sh[t+st]; __syncthreads(); }
    if (t == 0) biasT[h*4096 + j*64 + i] = sh[0] + rdf<DT>(b2v, h);
    __syncthreads();
  }
}

// ---------- K4: fused AGN: x -> xn2 (bf16), 32x32 tiles ----------
template<int DT>
__global__ __launch_bounds__(256) void k_agn_fused(const void* __restrict__ x,
    const float* __restrict__ stats,
    const void* la1w, const void* la1b, const void* la2w, const void* la2b,
    const void* ta1w, const void* ta1b, const void* ta2w, const void* ta2b,
    const void* agnw, const void* agnb,
    bf16* __restrict__ xn2, const int* __restrict__ flag){
  if (*flag != DT) return;
  __shared__ float xs[1296];   // 36x36 zero-padded
  __shared__ float ts[1156];   // 34x34
  __shared__ float us[1156];
  int idx = blockIdx.x;
  int tile = idx & 63; int bc = idx >> 6; int c = bc % 96; int b = bc / 96;
  int oy = (tile >> 3) << 5, ox = (tile & 7) << 5;
  float mean = stats[b], sd = stats[4+b];
  size_t xbase = ((size_t)bc) << 16;
  for (int it = threadIdx.x; it < 1296; it += 256){
    int ly = it / 36, lx = it % 36;
    int gy = oy - 2 + ly, gx = ox - 2 + lx;
    float v = 0.f;
    if (gy >= 0 && gy < 256 && gx >= 0 && gx < 256)
      v = (rdf<DT>(x, xbase + (gy<<8) + gx) - mean) / sd;
    xs[it] = v;
  }
  float wl1[9], wt1[9], wl2[9], wt2[9];
  #pragma unroll
  for (int k = 0; k < 9; k++){
    wl1[k] = rdf<DT>(la1w, c*9+k); wt1[k] = rdf<DT>(ta1w, c*9+k);
    wl2[k] = rdf<DT>(la2w, c*9+k); wt2[k] = rdf<DT>(ta2w, c*9+k);
  }
  float bl1 = rdf<DT>(la1b, c), bt1 = rdf<DT>(ta1b, c);
  __syncthreads();
  for (int it = threadIdx.x; it < 1156; it += 256){
    int ly = it / 34, lx = it % 34;
    int cy = oy - 1 + ly, cx = ox - 1 + lx;
    float a1 = 0.f, a2 = 0.f;
    if (cy >= 0 && cy < 256 && cx >= 0 && cx < 256){
      a1 = bl1; a2 = bt1;
      #pragma unroll
      for (int dy = 0; dy < 3; dy++)
        #pragma unroll
        for (int dx = 0; dx < 3; dx++){
          float v = xs[(ly+dy)*36 + lx+dx];
          a1 += v * wl1[dy*3+dx]; a2 += v * wt1[dy*3+dx];
        }
      a1 = fmaxf(a1, 0.f); a2 = fmaxf(a2, 0.f);
    }
    ts[it] = a1; us[it] = a2;
  }
  __syncthreads();
  float agw = rdf<DT>(agnw,c)*stats[8+bc];
  float agb = rdf<DT>(agnb,c) + stats[392+bc];
  float bl2 = rdf<DT>(la2b, c), bt2 = rdf<DT>(ta2b, c);
  #pragma unroll
  for (int k = 0; k < 4; k++){
    int px = threadIdx.x + (k << 8);
    int ly = px >> 5, lx = px & 31;
    float l = bl2, t = bt2;
    #pragma unroll
    for (int dy = 0; dy < 3; dy++)
      #pragma unroll
      for (int dx = 0; dx < 3; dx++){
        l += ts[(ly+dy)*34 + lx+dx] * wl2[dy*3+dx];
        t += us[(ly+dy)*34 + lx+dx] * wt2[dy*3+dx];
      }
    float v = xs[(ly+2)*36 + lx+2];
    float r = v*agw + agb + l + t;
    xn2[xbase + ((oy+ly)<<8) + ox + lx] = f2b(r);
  }
}

// ---------- K5: MFMA mega window kernel, 3 blocks/CU (round-4 verified state) ----------
// LDS arena 53760 B, overlaid regions (all transitions barrier-separated):
//  CS @0      short[64][104]  = 13312  (P2-P4)  conv-q, [n][c]
//  XS @13312  short[144][104] = 29952  (P1-P2)  halo, [t][c]
//  QB @43264  short[8][148] x4 waves = 9472 (P2)  per-wave half-Q scratch
//  KT @13312  short[64][104]  = 13312  (P3-P4)  K, [m][d], pre-scaled (over XS)
//  VD @26624  short[96][72]   = 13824  (P3-P4)  V, [d][m] (over XS)
//  XC @40448  short[64][104]  = 13312  (P3)     centers [n][c] (over XS/QB tail)
//  PS @40448  short[16][72] x4 waves = 9216 (P4)  per-wave P scratch (over XC)
//  OS @13312  short[64][104]  = 13312  (P5)     attn out [n][d] (over KT)
#define CS_OFF 0
#define XS_OFF 13312
#define QB_OFF 43264
#define KT_OFF 13312
#define VD_OFF 26624
#define XC_OFF 40448
#define PS_OFF 40448
#define OS_OFF 13312

template<int DT>
__global__ __launch_bounds__(256, 3) void k_attn_mega(const bf16* __restrict__ xn2,
    const void* qw, const void* qb, const void* kvw, const void* kvb,
    const void* dww, const void* dwb, const void* pw, const void* pb,
    const void* lsin, const float* __restrict__ biasT,
    const void* __restrict__ xin, const float* __restrict__ stats,
    void* __restrict__ outp, const int* __restrict__ flag){
  if (*flag != DT) return;
  __shared__ __align__(16) char smem[53760];
  int tid = threadIdx.x, wid = blockIdx.x;
  int b = wid >> 10, wy = (wid >> 5) & 31, wx = wid & 31;
  int wv = tid >> 6, ln = tid & 63;
  int r = ln & 15, q = ln >> 4;

  // ---- P1: stage reflected 12x12 halo, pixel-major xs[t][c].
  // Lane->channel assignment XORed by (t>>3)&7: spreads the 52-dword-stride
  // column writes from 8-way to ~2-way bank conflict; layout stays standard.
  {
    short* xs = (short*)(smem + XS_OFF);
    for (int it = tid; it < 13824; it += 256){
      int t = it % 144, craw = it / 144;
      int c = craw ^ ((t >> 3) & 7);
      int ty = (wy<<3) - 2 + t/12, tx = (wx<<3) - 2 + t%12;
      ty = ty < 0 ? -ty : (ty > 255 ? 510 - ty : ty);
      tx = tx < 0 ? -tx : (tx > 255 ? 510 - tx : tx);
      xs[t*104 + c] = ((const short*)xn2)[(((size_t)(b*96 + c))<<16) + (ty<<8) + tx];
    }
  }
  __syncthreads();

  // ---- P2: Q GEMM (M=96,N=144,K=96) + 5x5 dwconv, half-QB (8 ch) scratch.
  // 16-row MFMA output kept in regs (accs[9][4]); written+convolved in two
  // 8-channel halves so per-wave scratch is [8][148] instead of [16][148].
  {
    const short* xs = (const short*)(smem + XS_OFF);
    short* Qb = (short*)(smem + QB_OFF) + wv*1184;   // [8][148] shorts
    short* cs = (short*)(smem + CS_OFF);
    int ty0 = (ln>>3)+2, tx0 = (ln&7)+2;
    for (int mt = wv; mt < 6; mt += 4){
      short8v aw[3];
      #pragma unroll
      for (int kt = 0; kt < 3; kt++)
        aw[kt] = ld8<DT>(qw, (size_t)(16*mt + r)*96 + 32*kt + 8*q);
      float qb4[4];
      #pragma unroll
      for (int j = 0; j < 4; j++) qb4[j] = rdf<DT>(qb, 16*mt + 4*q + j);
      float accs[9][4];
      #pragma unroll
      for (int nt = 0; nt < 9; nt++){
        f32x4 acc = {0.f,0.f,0.f,0.f};
        #pragma unroll
        for (int kt = 0; kt < 3; kt++){
          short8v bx = *(const short8v*)(xs + (16*nt + r)*104 + 32*kt + 8*q);
          acc = __builtin_amdgcn_mfma_f32_16x16x32_bf16(aw[kt], bx, acc, 0, 0, 0);
        }
        #pragma unroll
        for (int j = 0; j < 4; j++) accs[nt][j] = acc[j] + qb4[j];
      }
      // half A: rows 0..7 (lanes q<2)
      if (q < 2){
        #pragma unroll
        for (int nt = 0; nt < 9; nt++)
          #pragma unroll
          for (int j = 0; j < 4; j++)
            Qb[(4*q+j)*148 + 16*nt + r] = f2bs(accs[nt][j]);
      }
      asm volatile("s_waitcnt lgkmcnt(0)" ::: "memory");
      for (int cl = 0; cl < 8; cl++){
        int c = 16*mt + cl;
        float a = rdf<DT>(dwb, c);
        #pragma unroll
        for (int dy = -2; dy <= 2; dy++)
          #pragma unroll
          for (int dx = -2; dx <= 2; dx++)
            a += bs2f(Qb[cl*148 + (ty0+dy)*12 + tx0+dx]) * rdf<DT>(dww, c*25 + (dy+2)*5 + dx+2);
        cs[ln*104 + c] = f2bs(a);
      }
      asm volatile("s_waitcnt lgkmcnt(0)" ::: "memory");
      // half B: rows 8..15 (lanes q>=2)
      if (q >= 2){
        #pragma unroll
        for (int nt = 0; nt < 9; nt++)
          #pragma unroll
          for (int j = 0; j < 4; j++)
            Qb[(4*(q-2)+j)*148 + 16*nt + r] = f2bs(accs[nt][j]);
      }
      asm volatile("s_waitcnt lgkmcnt(0)" ::: "memory");
      for (int cl = 8; cl < 16; cl++){
        int c = 16*mt + cl;
        float a = rdf<DT>(dwb, c);
        #pragma unroll
        for (int dy = -2; dy <= 2; dy++)
          #pragma unroll
          for (int dx = -2; dx <= 2; dx++)
            a += bs2f(Qb[(cl-8)*148 + (ty0+dy)*12 + tx0+dx]) * rdf<DT>(dww, c*25 + (dy+2)*5 + dx+2);
        cs[ln*104 + c] = f2bs(a);
      }
      asm volatile("s_waitcnt lgkmcnt(0)" ::: "memory");
    }
  }
  __syncthreads();

  // ---- P3: re-stage centers xc[n][c] (px^row write order: 16-way -> 2-way),
  //          then KV GEMM (M=192,N=64,K=96)
  {
    short* xc = (short*)(smem + XC_OFF);
    for (int it = tid; it < 768; it += 256){
      int c = it >> 3, row = it & 7;
      const short* src = (const short*)xn2 + (((size_t)(b*96 + c))<<16)
                         + (((wy<<3)+row)<<8) + (wx<<3);
      short8v v = *(const short8v*)src;
      #pragma unroll
      for (int k = 0; k < 8; k++){
        int pe = k ^ row;
        xc[(row*8+pe)*104 + c] = v[pe];
      }
    }
  }
  __syncthreads();
  {
    const short* xc = (const short*)(smem + XC_OFF);
    short* Kt = (short*)(smem + KT_OFF);
    short* Vd = (short*)(smem + VD_OFF);
    for (int mtk = wv; mtk < 12; mtk += 4){
      short8v aw[3];
      #pragma unroll
      for (int kt = 0; kt < 3; kt++)
        aw[kt] = ld8<DT>(kvw, (size_t)(16*mtk + r)*96 + 32*kt + 8*q);
      float bb[4];
      #pragma unroll
      for (int j = 0; j < 4; j++) bb[j] = rdf<DT>(kvb, 16*mtk + 4*q + j);
      for (int nt = 0; nt < 4; nt++){
        f32x4 acc = {0.f,0.f,0.f,0.f};
        #pragma unroll
        for (int kt = 0; kt < 3; kt++){
          short8v bx = *(const short8v*)(xc + (16*nt + r)*104 + 32*kt + 8*q);
          acc = __builtin_amdgcn_mfma_f32_16x16x32_bf16(aw[kt], bx, acc, 0, 0, 0);
        }
        if (mtk < 6){
          short4v kv;
          #pragma unroll
          for (int j = 0; j < 4; j++) kv[j] = f2bs((acc[j] + bb[j]) * SCALE_F);
          *(short4v*)(Kt + (16*nt + r)*104 + 16*mtk + 4*q) = kv;
        } else {
          #pragma unroll
          for (int j = 0; j < 4; j++)
            Vd[(16*(mtk-6) + 4*q + j)*72 + 16*nt + r] = f2bs(acc[j] + bb[j]);
        }
      }
    }
  }
  __syncthreads();

  // ---- P4: attention. Wave wv owns n-tile nt=wv for all 3 heads.
  float o_save[24];
  {
    const short* cs = (const short*)(smem + CS_OFF);
    const short* Kt = (const short*)(smem + KT_OFF);
    const short* Vd = (const short*)(smem + VD_OFF);
    short* Psw = (short*)(smem + PS_OFF) + wv*1152;   // [16][72]
    float lsv = __expf(fminf(rdf<DT>(lsin, 0), LOGIT_MAX_F));
    #pragma unroll
    for (int h = 0; h < 3; h++){
      short8v qa = *(const short8v*)(cs + (16*wv + r)*104 + 32*h + 8*q);
      f32x4 s[4];
      #pragma unroll
      for (int mt = 0; mt < 4; mt++){
        short8v kb = *(const short8v*)(Kt + (16*mt + r)*104 + 32*h + 8*q);
        f32x4 z = {0.f,0.f,0.f,0.f};
        s[mt] = __builtin_amdgcn_mfma_f32_16x16x32_bf16(qa, kb, z, 0, 0, 0);
      }
      float l[4][4];
      #pragma unroll
      for (int mt = 0; mt < 4; mt++){
        float4 bv = *(const float4*)(biasT + h*4096 + (16*mt + r)*64 + 16*wv + 4*q);
        l[mt][0] = s[mt][0]*lsv + bv.x;
        l[mt][1] = s[mt][1]*lsv + bv.y;
        l[mt][2] = s[mt][2]*lsv + bv.z;
        l[mt][3] = s[mt][3]*lsv + bv.w;
      }
      float mx[4], sm[4];
      #pragma unroll
      for (int j = 0; j < 4; j++){
        float m0 = fmaxf(fmaxf(l[0][j], l[1][j]), fmaxf(l[2][j], l[3][j]));
        m0 = fmaxf(m0, __shfl_xor(m0, 1));
        m0 = fmaxf(m0, __shfl_xor(m0, 2));
        m0 = fmaxf(m0, __shfl_xor(m0, 4));
        m0 = fmaxf(m0, __shfl_xor(m0, 8));
        mx[j] = m0; sm[j] = 0.f;
      }
      #pragma unroll
      for (int mt = 0; mt < 4; mt++)
        #pragma unroll
        for (int j = 0; j < 4; j++){
          float p = __expf(l[mt][j] - mx[j]);
          sm[j] += p;
          Psw[(4*q+j)*72 + 16*mt + r] = f2bs(p);
        }
      #pragma unroll
      for (int j = 0; j < 4; j++){
        sm[j] += __shfl_xor(sm[j], 1);
        sm[j] += __shfl_xor(sm[j], 2);
        sm[j] += __shfl_xor(sm[j], 4);
        sm[j] += __shfl_xor(sm[j], 8);
      }
      float inv[4];
      #pragma unroll
      for (int j = 0; j < 4; j++) inv[j] = 1.f / sm[j];
      asm volatile("s_waitcnt lgkmcnt(0)" ::: "memory");
      short8v pa0 = *(const short8v*)(Psw + r*72 + 8*q);
      short8v pa1 = *(const short8v*)(Psw + r*72 + 32 + 8*q);
      #pragma unroll
      for (int dt = 0; dt < 2; dt++){
        f32x4 o = {0.f,0.f,0.f,0.f};
        short8v vb0 = *(const short8v*)(Vd + (32*h + 16*dt + r)*72 + 8*q);
        short8v vb1 = *(const short8v*)(Vd + (32*h + 16*dt + r)*72 + 32 + 8*q);
        o = __builtin_amdgcn_mfma_f32_16x16x32_bf16(pa0, vb0, o, 0, 0, 0);
        o = __builtin_amdgcn_mfma_f32_16x16x32_bf16(pa1, vb1, o, 0, 0, 0);
        #pragma unroll
        for (int j = 0; j < 4; j++) o_save[h*8 + dt*4 + j] = o[j] * inv[j];
      }
      asm volatile("s_waitcnt lgkmcnt(0)" ::: "memory");
    }
  }
  __syncthreads();

  // ---- write osT[n][d] over KT region
  {
    short* os = (short*)(smem + OS_OFF);
    #pragma unroll
    for (int h = 0; h < 3; h++)
      #pragma unroll
      for (int dt = 0; dt < 2; dt++)
        #pragma unroll
        for (int j = 0; j < 4; j++)
          os[(16*wv + 4*q + j)*104 + 32*h + 16*dt + r] = f2bs(o_save[h*8 + dt*4 + j]);
  }
  __syncthreads();

  // ---- P5: proj GEMM (M=96,N=64,K=96) + residual epilogue
  {
    const short* os = (const short*)(smem + OS_OFF);
    short8v ob[3];
    #pragma unroll
    for (int kt = 0; kt < 3; kt++)
      ob[kt] = *(const short8v*)(os + (16*wv + r)*104 + 32*kt + 8*q);
    for (int mt = 0; mt < 6; mt++){
      f32x4 acc = {0.f,0.f,0.f,0.f};
      #pragma unroll
      for (int kt = 0; kt < 3; kt++){
        short8v aw = ld8<DT>(pw, (size_t)(16*mt + r)*96 + 32*kt + 8*q);
        acc = __builtin_amdgcn_mfma_f32_16x16x32_bf16(aw, ob[kt], acc, 0, 0, 0);
      }
      #pragma unroll
      for (int j = 0; j < 4; j++){
        int oc = 16*mt + 4*q + j;
        int n  = 16*wv + r;
        int gy = (wy<<3) + (n>>3), gx = (wx<<3) + (n&7);
        size_t gi = (((size_t)(b*96 + oc))<<16) + (gy<<8) + gx;
        float a = acc[j] + rdf<DT>(pb, oc);
        float x1 = rdf<DT>(xin, gi) + a*stats[8 + b*96 + oc] + stats[392 + b*96 + oc];
        wrf<DT>(outp, gi, x1);
      }
    }
  }
}

// ---------- K6: MFMA MLP v2, N-blocked ----------
template<int DT>
__global__ __launch_bounds__(256) void k_mlp_mfma(void* __restrict__ io,
    const void* w1, const void* b1, const void* w2, const void* b2v,
    const int* __restrict__ flag){
  if (*flag != DT) return;
  __shared__ __align__(16) short x1s[256*104];   // [pixel][channel], 53248 B
  int blk = blockIdx.x; int b = blk >> 8; int pix0 = (blk & 255) << 8;
  int tid = threadIdx.x;

  for (int c = 0; c < 96; c++){
    size_t gi = (((size_t)(b*96 + c))<<16) + pix0 + tid;
    short v = DT ? f2bs(((const float*)io)[gi]) : ((const short*)io)[gi];
    x1s[tid*104 + c] = v;
  }
  __syncthreads();

  int wv = tid >> 6, l = tid & 63;
  int r = l & 15, q = l >> 4;
  int pbase = wv << 6;

  f32x4 acc2[6][4];
  #pragma unroll
  for (int mt = 0; mt < 6; mt++)
    #pragma unroll
    for (int nt = 0; nt < 4; nt++)
      acc2[mt][nt] = (f32x4){0.f,0.f,0.f,0.f};

  #pragma unroll 2
  for (int t = 0; t < 12; t++){
    short8v aA[3], aB[3];
    #pragma unroll
    for (int kt = 0; kt < 3; kt++){
      aA[kt] = ld8<DT>(w1, (size_t)(32*t + r)*96      + 32*kt + 8*q);
      aB[kt] = ld8<DT>(w1, (size_t)(32*t + 16 + r)*96 + 32*kt + 8*q);
    }
    float bA[4], bB[4];
    #pragma unroll
    for (int j = 0; j < 4; j++){
      bA[j] = rdf<DT>(b1, 32*t + 4*q + j);
      bB[j] = rdf<DT>(b1, 32*t + 16 + 4*q + j);
    }
    f32x4 a1A[4], a1B[4];
    #pragma unroll
    for (int nt = 0; nt < 4; nt++){
      a1A[nt] = (f32x4){0.f,0.f,0.f,0.f};
      a1B[nt] = (f32x4){0.f,0.f,0.f,0.f};
    }
    #pragma unroll
    for (int kt = 0; kt < 3; kt++){
      #pragma unroll
      for (int nt = 0; nt < 4; nt++){
        short8v bx = *(const short8v*)&x1s[(pbase + 16*nt + r)*104 + 32*kt + 8*q];
        a1A[nt] = __builtin_amdgcn_mfma_f32_16x16x32_bf16(aA[kt], bx, a1A[nt], 0, 0, 0);
        a1B[nt] = __builtin_amdgcn_mfma_f32_16x16x32_bf16(aB[kt], bx, a1B[nt], 0, 0, 0);
      }
    }
    short8v B2[4];
    #pragma unroll
    for (int nt = 0; nt < 4; nt++){
      short8v h;
      #pragma unroll
      for (int j = 0; j < 4; j++){
        h[j]   = f2bs(fmaxf(a1A[nt][j] + bA[j], 0.f));
        h[4+j] = f2bs(fmaxf(a1B[nt][j] + bB[j], 0.f));
      }
      B2[nt] = h;
    }
    #pragma unroll
    for (int mt = 0; mt < 6; mt++){
      short8v wA = ld4x2<DT>(w2, (size_t)(16*mt + r)*384 + 32*t + 4*q);
      #pragma unroll
      for (int nt = 0; nt < 4; nt++)
        acc2[mt][nt] = __builtin_amdgcn_mfma_f32_16x16x32_bf16(wA, B2[nt], acc2[mt][nt], 0, 0, 0);
    }
  }

  #pragma unroll
  for (int mt = 0; mt < 6; mt++)
    #pragma unroll
    for (int nt = 0; nt < 4; nt++)
      #pragma unroll
      for (int j = 0; j < 4; j++){
        int oc = 16*mt + 4*q + j;
        int pl = pbase + 16*nt + r;
        size_t gi = (((size_t)(b*96 + oc))<<16) + pix0 + pl;
        float v = acc2[mt][nt][j] + rdf<DT>(b2v, oc);
        if (DT){
          ((float*)io)[gi] = ((const float*)io)[gi] + v;
        } else {
          ((bf16*)io)[gi] = f2b(bs2f(x1s[pl*104 + oc]) + v);
        }
      }
}

extern "C" void kernel_launch(void* const* d_in, const int* in_sizes, int n_in,
                              void* d_out, int out_size, void* d_ws, size_t ws_size,
                              hipStream_t stream) {
  const void* x      = d_in[0];
  const void* agnw   = d_in[1];
  const void* agnb   = d_in[2];
  const void* meta1w = d_in[3];
  const void* meta1b = d_in[4];
  const void* meta2w = d_in[5];
  const void* meta2b = d_in[6];
  const void* la1w   = d_in[7];
  const void* la1b   = d_in[8];
  const void* la2w   = d_in[9];
  const void* la2b   = d_in[10];
  const void* ta1w   = d_in[11];
  const void* ta1b   = d_in[12];
  const void* ta2w   = d_in[13];
  const void* ta2b   = d_in[14];
  const void* qw     = d_in[15];
  const void* qb     = d_in[16];
  const void* kvw    = d_in[17];
  const void* kvb    = d_in[18];
  const void* dww    = d_in[19];
  const void* dwb    = d_in[20];
  const void* pw     = d_in[21];
  const void* pb     = d_in[22];
  const void* lsin   = d_in[23];
  const void* rpw1   = d_in[24];
  const void* rpb1   = d_in[25];
  const void* rpw2   = d_in[26];
  const void* rpb2   = d_in[27];
  const void* m1w    = d_in[28];
  const void* m1b    = d_in[29];
  const void* m2w    = d_in[30];
  const void* m2b    = d_in[31];

  // ws: flag @0 | partials @256 | stats @8448 | biasT @12288 | xn2 @65536 (48MB)
  char* ws = (char*)d_ws;
  int*   flag     = (int*)ws;
  float* partials = (float*)(ws + 256);
  float* stats    = (float*)(ws + 8448);
  float* biasT    = (float*)(ws + 12288);
  bf16*  xn2      = (bf16*)(ws + 65536);

  k_detect<<<1, 256, 0, stream>>>(x, flag);

  // bf16 variant
  k_stats_partial<0><<<1024, 256, 0, stream>>>(x, partials, flag);
  k_stats_final<0>  <<<1,    256, 0, stream>>>(partials, meta1w, meta1b, meta2w, meta2b, stats, flag);
  k_bias<0>         <<<4096, 256, 0, stream>>>(rpw1, rpb1, rpw2, rpb2, biasT, flag);
  k_agn_fused<0>    <<<24576,256, 0, stream>>>(x, stats, la1w, la1b, la2w, la2b,
                                               ta1w, ta1b, ta2w, ta2b, agnw, agnb, xn2, flag);
  k_attn_mega<0>    <<<4096, 256, 0, stream>>>(xn2, qw, qb, kvw, kvb, dww, dwb, pw, pb,
                                               lsin, biasT, x, stats, d_out, flag);
  k_mlp_mfma<0>     <<<1024, 256, 0, stream>>>(d_out, m1w, m1b, m2w, m2b, flag);

  // fp32 variant
  k_stats_partial<1><<<1024, 256, 0, stream>>>(x, partials, flag);
  k_stats_final<1>  <<<1,    256, 0, stream>>>(partials, meta1w, meta1b, meta2w, meta2b, stats, flag);
  k_bias<1>         <<<4096, 256, 0, stream>>>(rpw1, rpb1, rpw2, rpb2, biasT, flag);
  k_agn_fused<1>    <<<24576,256, 0, stream>>>(x, stats, la1w, la1b, la2w, la2b,
                                               ta1w, ta1b, ta2w, ta2b, agnw, agnb, xn2, flag);
  k_attn_mega<1>    <<<4096, 256, 0, stream>>>(xn2, qw, qb, kvw, kvb, dww, dwb, pw, pb,
                                               lsin, biasT, x, stats, d_out, flag);
  k_mlp_mfma<1>     <<<1024, 256, 0, stream>>>(d_out, m1w, m1b, m2w, m2b, flag);
}